// Round 1
// baseline (212.329 us; speedup 1.0000x reference)
//
#include <hip/hip_runtime.h>

#define N_NODES 50000
#define K 32
#define NSEL 16
#define D 128
#define DOUT 64

// Kernel A: mlp2[n] = tanh(feat[n] @ W_mlp + b_mlp), C=2. One wave per node.
__global__ __launch_bounds__(256) void mlp_kernel(
    const float* __restrict__ feat, const float* __restrict__ Wm,
    const float* __restrict__ bm, float2* __restrict__ mlp2) {
  int wid = (blockIdx.x * blockDim.x + threadIdx.x) >> 6;
  int lane = threadIdx.x & 63;
  if (wid >= N_NODES) return;
  // lane l handles input dims 2l, 2l+1
  float2 f = *(const float2*)(feat + (size_t)wid * D + lane * 2);
  float4 w = *(const float4*)(Wm + lane * 4);  // W[2l][0],W[2l][1],W[2l+1][0],W[2l+1][1]
  float p0 = f.x * w.x + f.y * w.z;
  float p1 = f.x * w.y + f.y * w.w;
#pragma unroll
  for (int off = 32; off; off >>= 1) {
    p0 += __shfl_xor(p0, off);
    p1 += __shfl_xor(p1, off);
  }
  if (lane == 0) {
    mlp2[wid] = make_float2(tanhf(p0 + bm[0]), tanhf(p1 + bm[1]));
  }
}

// Kernel B: per node — 3x {L1 dist, select 16 smallest, mean-gather feat rows},
// residual + tanh, then 128x64 matmul epilogue. One wave per node, 4 waves/block.
__global__ __launch_bounds__(256) void care_kernel(
    const float* __restrict__ feat, const float2* __restrict__ mlp2,
    const int* __restrict__ nbr0, const int* __restrict__ nbr1,
    const int* __restrict__ nbr2, const float* __restrict__ Wl,
    const float* __restrict__ bl, float* __restrict__ out) {
  __shared__ float sW[D * DOUT];  // 32 KB: W_lin staged
  __shared__ float sH[4][D];      // 2 KB: per-wave h_homo row

  // Stage W_lin (2048 float4 / 256 threads = 8 each, coalesced)
  for (int i = threadIdx.x; i < (D * DOUT) / 4; i += blockDim.x)
    ((float4*)sW)[i] = ((const float4*)Wl)[i];

  const int wave = threadIdx.x >> 6;
  const int lane = threadIdx.x & 63;
  const int n = blockIdx.x * 4 + wave;  // grid sized exactly: 12500*4 = 50000

  const float2 my = mlp2[n];
  // residual: start accumulator at feat[n]
  float2 acc = *(const float2*)(feat + (size_t)n * D + lane * 2);

  const int* nbrs[3] = {nbr0, nbr1, nbr2};
#pragma unroll 1
  for (int e = 0; e < 3; ++e) {
    const int* nb = nbrs[e];
    int src = 0;
    if (lane < K) src = nb[n * K + lane];
    float2 mh = mlp2[src];
    float d = fabsf(mh.x - my.x) + fabsf(mh.y - my.y);
    // rank = #{j : d_j < d_i || (d_j == d_i && j < i)}  (matches top_k tie-break)
    int cnt = 0;
#pragma unroll
    for (int j = 0; j < K; ++j) {
      float dj = __shfl(d, j);
      cnt += (dj < d) || (dj == d && j < lane);
    }
    bool sel = (lane < K) && (cnt < NSEL);
    unsigned long long mask = __ballot(sel);  // exactly NSEL bits set (ranks unique)
    float2 s = make_float2(0.f, 0.f);
#pragma unroll
    for (int t = 0; t < NSEL; ++t) {
      int j = __ffsll(mask) - 1;
      mask &= mask - 1;
      int sj = __shfl(src, j);
      float2 v = *(const float2*)(feat + (size_t)sj * D + lane * 2);
      s.x += v.x;
      s.y += v.y;
    }
    acc.x += 0.5f * tanhf(s.x * (1.f / NSEL));
    acc.y += 0.5f * tanhf(s.y * (1.f / NSEL));
  }
  acc.x = tanhf(acc.x);
  acc.y = tanhf(acc.y);
  sH[wave][lane * 2] = acc.x;
  sH[wave][lane * 2 + 1] = acc.y;
  __syncthreads();  // covers sW staging + sH writes

  // epilogue: lane j computes out[n][j] = b[j] + sum_i h[i] * W[i][j]
  float o = bl[lane];
  const float* h = sH[wave];
#pragma unroll 8
  for (int i = 0; i < D; ++i) o += h[i] * sW[i * DOUT + lane];
  out[(size_t)n * DOUT + lane] = o;
}

extern "C" void kernel_launch(void* const* d_in, const int* in_sizes, int n_in,
                              void* d_out, int out_size, void* d_ws,
                              size_t ws_size, hipStream_t stream) {
  const float* feat = (const float*)d_in[0];
  const float* Wm = (const float*)d_in[1];
  const float* bm = (const float*)d_in[2];
  const float* Wl = (const float*)d_in[3];
  const float* bl = (const float*)d_in[4];
  const int* nbr0 = (const int*)d_in[5];
  const int* nbr1 = (const int*)d_in[6];
  const int* nbr2 = (const int*)d_in[7];
  float* out = (float*)d_out;
  float2* mlp2 = (float2*)d_ws;  // 50000 * 8 B = 400 KB

  mlp_kernel<<<(N_NODES + 3) / 4, 256, 0, stream>>>(feat, Wm, bm, mlp2);
  care_kernel<<<N_NODES / 4, 256, 0, stream>>>(feat, mlp2, nbr0, nbr1, nbr2, Wl,
                                               bl, out);
}

// Round 4
// 150.378 us; speedup vs baseline: 1.4120x; 1.4120x over previous
//
#include <hip/hip_runtime.h>
#include <hip/hip_fp16.h>

#define N_NODES 50000
#define K 32
#define NSEL 16
#define D 128
#define DOUT 64

__device__ __forceinline__ float2 unpack_h2(unsigned int w) {
  union { unsigned int u; __half2 h; } c;
  c.u = w;
  return __half22float2(c.h);
}
__device__ __forceinline__ unsigned int pack_h2(float a, float b) {
  union { __half2 h; unsigned int u; } c;
  c.h = __floats2half2_rn(a, b);
  return c.u;
}
__device__ __forceinline__ float fast_tanh(float x) {
  x = fminf(10.f, fmaxf(-10.f, x));
  float e = __expf(2.f * x);
  return (e - 1.f) * __fdividef(1.f, e + 1.f);
}

// Kernel A: mlp2[n] = tanh(feat[n] @ W_mlp + b_mlp)  (C=2), and feath = fp16(feat).
// One wave per node. NOTE: must use libm tanhf here — mlp2 feeds the top-k
// selection distances; fast_tanh's ~1ulp error flips near-ties (R2/R3 failure).
__global__ __launch_bounds__(256) void mlp_kernel(
    const float* __restrict__ feat, const float* __restrict__ Wm,
    const float* __restrict__ bm, float2* __restrict__ mlp2,
    unsigned int* __restrict__ feath /* [N][D/2] packed half2 */) {
  int wid = (blockIdx.x * blockDim.x + threadIdx.x) >> 6;
  int lane = threadIdx.x & 63;
  if (wid >= N_NODES) return;
  float2 f = *(const float2*)(feat + (size_t)wid * D + lane * 2);
  float4 w = *(const float4*)(Wm + lane * 4);
  float p0 = f.x * w.x + f.y * w.z;
  float p1 = f.x * w.y + f.y * w.w;
#pragma unroll
  for (int off = 32; off; off >>= 1) {
    p0 += __shfl_xor(p0, off);
    p1 += __shfl_xor(p1, off);
  }
  feath[(size_t)wid * (D / 2) + lane] = pack_h2(f.x, f.y);
  if (lane == 0) {
    mlp2[wid] = make_float2(tanhf(p0 + bm[0]), tanhf(p1 + bm[1]));
  }
}

// Kernel B: per node — 3x {L1 dist over C=2, select 16 smallest, mean-gather
// fp16 feat rows (2 rows/pass, half-wave each)}, residual + tanh, then
// 128x64 matmul epilogue with fp16-packed W_lin in LDS.
__global__ __launch_bounds__(256, 6) void care_kernel(
    const float* __restrict__ feat, const unsigned int* __restrict__ feath,
    const float2* __restrict__ mlp2, const int* __restrict__ nbr0,
    const int* __restrict__ nbr1, const int* __restrict__ nbr2,
    const float* __restrict__ Wl, const float* __restrict__ bl,
    float* __restrict__ out) {
  __shared__ unsigned int sWh[(D / 2) * DOUT];  // 16 KB: word[p][j] = {W[2p][j], W[2p+1][j]} fp16
  __shared__ float sH[4][D];                    // 2 KB

  // Stage W_lin as packed fp16 pairs: 4096 words / 256 threads = 16 each.
  for (int idx = threadIdx.x; idx < (D / 2) * DOUT; idx += blockDim.x) {
    int p = idx >> 6, j = idx & 63;
    sWh[idx] = pack_h2(Wl[p * (2 * DOUT) + j], Wl[p * (2 * DOUT) + DOUT + j]);
  }

  const int wave = threadIdx.x >> 6;
  const int lane = threadIdx.x & 63;
  const int q = lane & 31;   // this lane accumulates dims 4q..4q+3
  const int half_id = lane >> 5;
  const int n = blockIdx.x * 4 + wave;  // grid = 12500 blocks exactly

  const float2 my = mlp2[n];
  // residual: acc starts at feat[n], dims 4q..4q+3 (duplicated across halves)
  float4 acc = *(const float4*)(feat + (size_t)n * D + q * 4);

  const int* nbrs[3] = {nbr0, nbr1, nbr2};
#pragma unroll 1
  for (int e = 0; e < 3; ++e) {
    const int* nb = nbrs[e];
    int src = 0;
    float d = 0.f;
    if (lane < K) {
      src = nb[n * K + lane];
      float2 mh = mlp2[src];
      d = fabsf(mh.x - my.x) + fabsf(mh.y - my.y);
    }
    // rank = #{j : d_j < d_i || (d_j == d_i && j < i)} — matches top_k tie-break
    int cnt = 0;
#pragma unroll
    for (int j = 0; j < K; ++j) {
      float dj = __shfl(d, j);
      cnt += (dj < d) || (dj == d && j < lane);
    }
    // push src to lane=rank (ranks unique 0..31 for lanes<K; others push to self)
    int dst = (lane < K) ? cnt : lane;
    int psrc = __builtin_amdgcn_ds_permute(dst << 2, src);
    // lanes 0..15 now hold the 16 selected src ids in rank order.
    float s0 = 0.f, s1 = 0.f, s2 = 0.f, s3 = 0.f;
#pragma unroll
    for (int t = 0; t < 8; ++t) {
      int row = __shfl(psrc, 2 * t + half_id);  // half-wave per row
      uint2 u = *(const uint2*)(feath + (size_t)row * (D / 2) + q * 2);
      float2 a = unpack_h2(u.x);
      float2 b = unpack_h2(u.y);
      s0 += a.x;
      s1 += a.y;
      s2 += b.x;
      s3 += b.y;
    }
    // combine the two half-wave partials (even-rank rows + odd-rank rows)
    s0 += __shfl_xor(s0, 32);
    s1 += __shfl_xor(s1, 32);
    s2 += __shfl_xor(s2, 32);
    s3 += __shfl_xor(s3, 32);
    acc.x += 0.5f * fast_tanh(s0 * (1.f / NSEL));
    acc.y += 0.5f * fast_tanh(s1 * (1.f / NSEL));
    acc.z += 0.5f * fast_tanh(s2 * (1.f / NSEL));
    acc.w += 0.5f * fast_tanh(s3 * (1.f / NSEL));
  }
  acc.x = fast_tanh(acc.x);
  acc.y = fast_tanh(acc.y);
  acc.z = fast_tanh(acc.z);
  acc.w = fast_tanh(acc.w);
  if (lane < 32) *(float4*)(&sH[wave][q * 4]) = acc;
  __syncthreads();  // covers sWh staging + sH writes

  // epilogue: lane j computes out[n][j]
  float o = bl[lane];
  const float* h = sH[wave];
#pragma unroll 8
  for (int p = 0; p < D / 2; ++p) {
    float2 w = unpack_h2(sWh[p * DOUT + lane]);
    float2 hp = *(const float2*)(h + 2 * p);
    o += hp.x * w.x + hp.y * w.y;
  }
  out[(size_t)n * DOUT + lane] = o;
}

extern "C" void kernel_launch(void* const* d_in, const int* in_sizes, int n_in,
                              void* d_out, int out_size, void* d_ws,
                              size_t ws_size, hipStream_t stream) {
  const float* feat = (const float*)d_in[0];
  const float* Wm = (const float*)d_in[1];
  const float* bm = (const float*)d_in[2];
  const float* Wl = (const float*)d_in[3];
  const float* bl = (const float*)d_in[4];
  const int* nbr0 = (const int*)d_in[5];
  const int* nbr1 = (const int*)d_in[6];
  const int* nbr2 = (const int*)d_in[7];
  float* out = (float*)d_out;
  float2* mlp2 = (float2*)d_ws;                                        // 400 KB
  unsigned int* feath = (unsigned int*)((char*)d_ws + (512 << 10));    // 12.8 MB

  mlp_kernel<<<(N_NODES + 3) / 4, 256, 0, stream>>>(feat, Wm, bm, mlp2, feath);
  care_kernel<<<N_NODES / 4, 256, 0, stream>>>(feat, feath, mlp2, nbr0, nbr1,
                                               nbr2, Wl, bl, out);
}

// Round 5
// 112.395 us; speedup vs baseline: 1.8891x; 1.3379x over previous
//
#include <hip/hip_runtime.h>
#include <hip/hip_fp16.h>

#define N_NODES 50000
#define K 32
#define NSEL 16
#define D 128
#define DOUT 64
#define NTILES (N_NODES / 16)  // 3125 MFMA node-tiles

typedef __attribute__((ext_vector_type(8))) _Float16 half8;
typedef __attribute__((ext_vector_type(4))) float floatx4;

__device__ __forceinline__ unsigned int pack_h2(float a, float b) {
  union { __half2 h; unsigned int u; } c;
  c.h = __floats2half2_rn(a, b);
  return c.u;
}
__device__ __forceinline__ __half2 as_h2(unsigned int u) {
  union { unsigned int u; __half2 h; } c;
  c.u = u;
  return c.h;
}
__device__ __forceinline__ unsigned int as_u32(__half2 h) {
  union { __half2 h; unsigned int u; } c;
  c.h = h;
  return c.u;
}
__device__ __forceinline__ float fast_tanh(float x) {
  x = fminf(10.f, fmaxf(-10.f, x));
  float e = __expf(2.f * x);
  return (e - 1.f) * __fdividef(1.f, e + 1.f);
}

// Kernel A: mlp2[n] = tanh(feat[n] @ W_mlp + b_mlp)  (C=2), feath = fp16(feat).
// libm tanhf here — mlp2 feeds top-k selection; fast_tanh flips near-ties.
__global__ __launch_bounds__(256) void mlp_kernel(
    const float* __restrict__ feat, const float* __restrict__ Wm,
    const float* __restrict__ bm, float2* __restrict__ mlp2,
    unsigned int* __restrict__ feath /* [N][D/2] packed half2 */) {
  int wid = (blockIdx.x * blockDim.x + threadIdx.x) >> 6;
  int lane = threadIdx.x & 63;
  if (wid >= N_NODES) return;
  float2 f = *(const float2*)(feat + (size_t)wid * D + lane * 2);
  float4 w = *(const float4*)(Wm + lane * 4);
  float p0 = f.x * w.x + f.y * w.z;
  float p1 = f.x * w.y + f.y * w.w;
#pragma unroll
  for (int off = 32; off; off >>= 1) {
    p0 += __shfl_xor(p0, off);
    p1 += __shfl_xor(p1, off);
  }
  feath[(size_t)wid * (D / 2) + lane] = pack_h2(f.x, f.y);
  if (lane == 0) {
    mlp2[wid] = make_float2(tanhf(p0 + bm[0]), tanhf(p1 + bm[1]));
  }
}

// Kernel B: per node — 3x {L1 dist, select 16 smallest (R4-identical path),
// mean-gather fp16 rows with packed half2 accumulation}, residual + tanh,
// store h as packed fp16 INTO d_out rows (256 B each). No LDS, no barrier.
__global__ __launch_bounds__(256) void care_kernel(
    const float* __restrict__ feat, const unsigned int* __restrict__ feath,
    const float2* __restrict__ mlp2, const int* __restrict__ nbr0,
    const int* __restrict__ nbr1, const int* __restrict__ nbr2,
    unsigned int* __restrict__ hfw /* aliases d_out; [N][64] words */) {
  const int lane = threadIdx.x & 63;
  const int q = lane & 31;   // this lane accumulates dims 4q..4q+3
  const int half_id = lane >> 5;
  const int n = blockIdx.x * 4 + (threadIdx.x >> 6);  // 12500 blocks exactly

  const float2 my = mlp2[n];
  float4 acc = *(const float4*)(feat + (size_t)n * D + q * 4);  // residual

  const int* nbrs[3] = {nbr0, nbr1, nbr2};
#pragma unroll 1
  for (int e = 0; e < 3; ++e) {
    const int* nb = nbrs[e];
    int src = 0;
    float d = 0.f;
    if (lane < K) {
      src = nb[n * K + lane];
      float2 mh = mlp2[src];
      d = fabsf(mh.x - my.x) + fabsf(mh.y - my.y);
    }
    // rank = #{j : d_j < d_i || (d_j == d_i && j < i)} — matches top_k tie-break
    int cnt = 0;
#pragma unroll
    for (int j = 0; j < K; ++j) {
      float dj = __shfl(d, j);
      cnt += (dj < d) || (dj == d && j < lane);
    }
    int dst = (lane < K) ? cnt : lane;
    int psrc = __builtin_amdgcn_ds_permute(dst << 2, src);
    // lanes 0..15 hold the 16 selected src ids in rank order.
    __half2 S0 = as_h2(0u), S1 = as_h2(0u);
#pragma unroll
    for (int t = 0; t < 8; ++t) {
      int row = __shfl(psrc, 2 * t + half_id);  // half-wave per row
      uint2 u = *(const uint2*)(feath + (size_t)row * (D / 2) + q * 2);
      S0 = __hadd2(S0, as_h2(u.x));
      S1 = __hadd2(S1, as_h2(u.y));
    }
    // combine the two half-wave partials (even-rank + odd-rank rows)
    S0 = __hadd2(S0, as_h2(__shfl_xor((int)as_u32(S0), 32)));
    S1 = __hadd2(S1, as_h2(__shfl_xor((int)as_u32(S1), 32)));
    float2 f0 = __half22float2(S0);
    float2 f1 = __half22float2(S1);
    acc.x += 0.5f * fast_tanh(f0.x * (1.f / NSEL));
    acc.y += 0.5f * fast_tanh(f0.y * (1.f / NSEL));
    acc.z += 0.5f * fast_tanh(f1.x * (1.f / NSEL));
    acc.w += 0.5f * fast_tanh(f1.y * (1.f / NSEL));
  }
  acc.x = fast_tanh(acc.x);
  acc.y = fast_tanh(acc.y);
  acc.z = fast_tanh(acc.z);
  acc.w = fast_tanh(acc.w);
  if (half_id == 0) {
    uint2 p;
    p.x = pack_h2(acc.x, acc.y);
    p.y = pack_h2(acc.z, acc.w);
    *(uint2*)(hfw + (size_t)n * (D / 2) + q * 2) = p;  // fp16 h row, 256 B
  }
}

// Kernel C: out[50000x64] = h[50000x128] @ W_lin + b_lin via fp16 MFMA.
// h is read fp16-packed from d_out rows and overwritten in place (each wave
// reads its full 16-row tile before storing). W staged as pre-swizzled
// B-fragments in LDS. A layout: m=lane&15, k=(lane>>4)*8+j. C: n=lane&15,
// m=(lane>>4)*4+reg (m89-verified).
__global__ __launch_bounds__(256) void gemm_kernel(
    const unsigned int* __restrict__ hfw, const float* __restrict__ Wl,
    const float* __restrict__ bl, float* __restrict__ out) {
  __shared__ _Float16 sB[16 * 64 * 8];  // 16 KB: [kk*4+nt][lane][8]

  // Stage W as B-fragments: word w = ((kk*4+nt)*64 + l)*4 + j2
  for (int w = threadIdx.x; w < 4096; w += blockDim.x) {
    int f = w >> 8, l = (w >> 2) & 63, j2 = w & 3;
    int kk = f >> 2, nt = f & 3;
    int k = kk * 32 + ((l >> 4) << 3) + 2 * j2;
    int nn = nt * 16 + (l & 15);
    ((unsigned int*)sB)[w] = pack_h2(Wl[k * DOUT + nn], Wl[(k + 1) * DOUT + nn]);
  }
  __syncthreads();

  const int lane = threadIdx.x & 63;
  const int tile = blockIdx.x * 4 + (threadIdx.x >> 6);
  if (tile >= NTILES) return;
  const int m0 = tile * 16;

  floatx4 acc[4];
  float b = bl[(lane & 15)];
#pragma unroll
  for (int nt = 0; nt < 4; ++nt) {
    float bn = bl[nt * 16 + (lane & 15)];
    acc[nt] = (floatx4){bn, bn, bn, bn};
  }
  const _Float16* hf = (const _Float16*)hfw;
#pragma unroll
  for (int kk = 0; kk < 4; ++kk) {
    half8 a = *(const half8*)(hf + (size_t)(m0 + (lane & 15)) * D + kk * 32 +
                              ((lane >> 4) << 3));
#pragma unroll
    for (int nt = 0; nt < 4; ++nt) {
      half8 bfr = *(const half8*)(sB + ((kk * 4 + nt) * 64 + lane) * 8);
      acc[nt] = __builtin_amdgcn_mfma_f32_16x16x32_f16(a, bfr, acc[nt], 0, 0, 0);
    }
  }
  (void)b;
#pragma unroll
  for (int nt = 0; nt < 4; ++nt) {
#pragma unroll
    for (int r = 0; r < 4; ++r) {
      int m = m0 + ((lane >> 4) << 2) + r;
      out[(size_t)m * DOUT + nt * 16 + (lane & 15)] = acc[nt][r];
    }
  }
}

extern "C" void kernel_launch(void* const* d_in, const int* in_sizes, int n_in,
                              void* d_out, int out_size, void* d_ws,
                              size_t ws_size, hipStream_t stream) {
  const float* feat = (const float*)d_in[0];
  const float* Wm = (const float*)d_in[1];
  const float* bm = (const float*)d_in[2];
  const float* Wl = (const float*)d_in[3];
  const float* bl = (const float*)d_in[4];
  const int* nbr0 = (const int*)d_in[5];
  const int* nbr1 = (const int*)d_in[6];
  const int* nbr2 = (const int*)d_in[7];
  float* out = (float*)d_out;
  float2* mlp2 = (float2*)d_ws;                                      // 400 KB
  unsigned int* feath = (unsigned int*)((char*)d_ws + (512 << 10));  // 12.8 MB

  mlp_kernel<<<(N_NODES + 3) / 4, 256, 0, stream>>>(feat, Wm, bm, mlp2, feath);
  care_kernel<<<N_NODES / 4, 256, 0, stream>>>(feat, feath, mlp2, nbr0, nbr1,
                                               nbr2, (unsigned int*)d_out);
  gemm_kernel<<<(NTILES + 3) / 4, 256, 0, stream>>>((const unsigned int*)d_out,
                                                    Wl, bl, out);
}

// Round 6
// 98.790 us; speedup vs baseline: 2.1493x; 1.1377x over previous
//
#include <hip/hip_runtime.h>
#include <hip/hip_fp16.h>

#define N_NODES 50000
#define K 32
#define NSEL 16
#define D 128
#define DOUT 64
#define NTILES (N_NODES / 16)  // 3125 MFMA node-tiles

typedef __attribute__((ext_vector_type(8))) _Float16 half8;
typedef __attribute__((ext_vector_type(4))) float floatx4;

__device__ __forceinline__ unsigned int pack_h2(float a, float b) {
  union { __half2 h; unsigned int u; } c;
  c.h = __floats2half2_rn(a, b);
  return c.u;
}
__device__ __forceinline__ __half2 as_h2(unsigned int u) {
  union { unsigned int u; __half2 h; } c;
  c.u = u;
  return c.h;
}
__device__ __forceinline__ float fast_tanh(float x) {
  x = fminf(10.f, fmaxf(-10.f, x));
  float e = __expf(2.f * x);
  return (e - 1.f) * __fdividef(1.f, e + 1.f);
}

// Kernel A: mlp2[n] = tanh(feat[n] @ W_mlp + b_mlp) (C=2), feath = fp16(feat).
// TWO nodes per wave: half-wave per node, lane owns dims 4*sub..4*sub+3.
// libm tanhf here — mlp2 feeds top-k selection; fast_tanh flips near-ties.
__global__ __launch_bounds__(256) void mlp_kernel(
    const float* __restrict__ feat, const float* __restrict__ Wm,
    const float* __restrict__ bm, float2* __restrict__ mlp2,
    unsigned int* __restrict__ feath /* [N][D/2] packed half2 */) {
  const int wid = (blockIdx.x * blockDim.x + threadIdx.x) >> 6;  // 0..24999
  const int lane = threadIdx.x & 63;
  const int sub = lane & 31;
  const int n = wid * 2 + (lane >> 5);

  float4 f = *(const float4*)(feat + (size_t)n * D + sub * 4);
  float4 w01 = *(const float4*)(Wm + sub * 8);      // W[4s][0..1],W[4s+1][0..1]
  float4 w23 = *(const float4*)(Wm + sub * 8 + 4);  // W[4s+2][..],W[4s+3][..]
  float p0 = f.x * w01.x + f.y * w01.z + f.z * w23.x + f.w * w23.z;
  float p1 = f.x * w01.y + f.y * w01.w + f.z * w23.y + f.w * w23.w;
#pragma unroll
  for (int off = 16; off; off >>= 1) {  // stays within the 32-lane half
    p0 += __shfl_xor(p0, off);
    p1 += __shfl_xor(p1, off);
  }
  uint2 pk;
  pk.x = pack_h2(f.x, f.y);
  pk.y = pack_h2(f.z, f.w);
  *(uint2*)(feath + n * (D / 2) + sub * 2) = pk;
  if (sub == 0) {
    mlp2[n] = make_float2(tanhf(p0 + bm[0]), tanhf(p1 + bm[1]));
  }
}

// Kernel B: TWO nodes per wave — per half-wave: {L1 dist (all 32 lanes = all
// 32 edges), rank via 32 ds_bpermute + compares (tie-break identical to
// top_k), ds_permute to rank-order, 16-pass full-row fp16 gather with packed
// half2 accumulation}, residual + tanh, store h fp16 into d_out rows.
__global__ __launch_bounds__(256) void care_kernel(
    const float* __restrict__ feat, const unsigned int* __restrict__ feath,
    const float2* __restrict__ mlp2, const int* __restrict__ nbr0,
    const int* __restrict__ nbr1, const int* __restrict__ nbr2,
    unsigned int* __restrict__ hfw /* aliases d_out; [N][64] words */) {
  const int lane = threadIdx.x & 63;
  const int sub = lane & 31;
  const int hbase = (lane & 32) << 2;  // DS byte addr of this half's lane 0
  const int wid = (blockIdx.x * blockDim.x + threadIdx.x) >> 6;  // 0..24999
  const int n = wid * 2 + (lane >> 5);

  const float2 my = mlp2[n];
  float4 acc = *(const float4*)(feat + (size_t)n * D + sub * 4);  // residual

  const int* nbrs[3] = {nbr0, nbr1, nbr2};
#pragma unroll 1
  for (int e = 0; e < 3; ++e) {
    const int src = nbrs[e][n * K + sub];
    const float2 mh = mlp2[src];
    const float d = fabsf(mh.x - my.x) + fabsf(mh.y - my.y);
    // rank within half = #{j : d_j < d_i || (d_j == d_i && j < i)}
    int cnt = 0;
#pragma unroll
    for (int j = 0; j < K; ++j) {
      float dj = __int_as_float(
          __builtin_amdgcn_ds_bpermute(hbase + 4 * j, __float_as_int(d)));
      cnt += (dj < d) || (dj == d && j < sub);
    }
    // push src to lane hbase/4 + rank; lanes {h*32..h*32+15} hold selected ids
    int psrc = __builtin_amdgcn_ds_permute(hbase + (cnt << 2), src);
    __half2 S0 = as_h2(0u), S1 = as_h2(0u);
#pragma unroll
    for (int t = 0; t < NSEL; ++t) {
      int row = __builtin_amdgcn_ds_bpermute(hbase + 4 * t, psrc);
      unsigned idx = (unsigned)(row * (D / 2) + sub * 2);
      uint2 u = *(const uint2*)(feath + idx);
      S0 = __hadd2(S0, as_h2(u.x));
      S1 = __hadd2(S1, as_h2(u.y));
    }
    float2 f0 = __half22float2(S0);
    float2 f1 = __half22float2(S1);
    acc.x += 0.5f * fast_tanh(f0.x * (1.f / NSEL));
    acc.y += 0.5f * fast_tanh(f0.y * (1.f / NSEL));
    acc.z += 0.5f * fast_tanh(f1.x * (1.f / NSEL));
    acc.w += 0.5f * fast_tanh(f1.y * (1.f / NSEL));
  }
  acc.x = fast_tanh(acc.x);
  acc.y = fast_tanh(acc.y);
  acc.z = fast_tanh(acc.z);
  acc.w = fast_tanh(acc.w);
  uint2 p;
  p.x = pack_h2(acc.x, acc.y);
  p.y = pack_h2(acc.z, acc.w);
  *(uint2*)(hfw + n * (D / 2) + sub * 2) = p;  // fp16 h row, 256 B/node
}

// Kernel C: out[50000x64] = h[50000x128] @ W_lin + b_lin via fp16 MFMA.
// h read fp16-packed from d_out rows, overwritten in place (each wave reads
// its full 16-row tile before storing). A: m=lane&15, k=(lane>>4)*8+j.
// C: n=lane&15, m=(lane>>4)*4+reg (m89-verified).
__global__ __launch_bounds__(256) void gemm_kernel(
    const unsigned int* __restrict__ hfw, const float* __restrict__ Wl,
    const float* __restrict__ bl, float* __restrict__ out) {
  __shared__ _Float16 sB[16 * 64 * 8];  // 16 KB: [kk*4+nt][lane][8]

  for (int w = threadIdx.x; w < 4096; w += blockDim.x) {
    int f = w >> 8, l = (w >> 2) & 63, j2 = w & 3;
    int kk = f >> 2, nt = f & 3;
    int k = kk * 32 + ((l >> 4) << 3) + 2 * j2;
    int nn = nt * 16 + (l & 15);
    ((unsigned int*)sB)[w] = pack_h2(Wl[k * DOUT + nn], Wl[(k + 1) * DOUT + nn]);
  }
  __syncthreads();

  const int lane = threadIdx.x & 63;
  const int tile = blockIdx.x * 4 + (threadIdx.x >> 6);
  if (tile >= NTILES) return;
  const int m0 = tile * 16;

  floatx4 acc[4];
#pragma unroll
  for (int nt = 0; nt < 4; ++nt) {
    float bn = bl[nt * 16 + (lane & 15)];
    acc[nt] = (floatx4){bn, bn, bn, bn};
  }
  const _Float16* hf = (const _Float16*)hfw;
#pragma unroll
  for (int kk = 0; kk < 4; ++kk) {
    half8 a = *(const half8*)(hf + (size_t)(m0 + (lane & 15)) * D + kk * 32 +
                              ((lane >> 4) << 3));
#pragma unroll
    for (int nt = 0; nt < 4; ++nt) {
      half8 bfr = *(const half8*)(sB + ((kk * 4 + nt) * 64 + lane) * 8);
      acc[nt] = __builtin_amdgcn_mfma_f32_16x16x32_f16(a, bfr, acc[nt], 0, 0, 0);
    }
  }
#pragma unroll
  for (int nt = 0; nt < 4; ++nt) {
#pragma unroll
    for (int r = 0; r < 4; ++r) {
      int m = m0 + ((lane >> 4) << 2) + r;
      out[(size_t)m * DOUT + nt * 16 + (lane & 15)] = acc[nt][r];
    }
  }
}

extern "C" void kernel_launch(void* const* d_in, const int* in_sizes, int n_in,
                              void* d_out, int out_size, void* d_ws,
                              size_t ws_size, hipStream_t stream) {
  const float* feat = (const float*)d_in[0];
  const float* Wm = (const float*)d_in[1];
  const float* bm = (const float*)d_in[2];
  const float* Wl = (const float*)d_in[3];
  const float* bl = (const float*)d_in[4];
  const int* nbr0 = (const int*)d_in[5];
  const int* nbr1 = (const int*)d_in[6];
  const int* nbr2 = (const int*)d_in[7];
  float* out = (float*)d_out;
  float2* mlp2 = (float2*)d_ws;                                      // 400 KB
  unsigned int* feath = (unsigned int*)((char*)d_ws + (512 << 10));  // 12.8 MB

  mlp_kernel<<<N_NODES / 8, 256, 0, stream>>>(feat, Wm, bm, mlp2, feath);
  care_kernel<<<N_NODES / 8, 256, 0, stream>>>(feat, feath, mlp2, nbr0, nbr1,
                                               nbr2, (unsigned int*)d_out);
  gemm_kernel<<<(NTILES + 3) / 4, 256, 0, stream>>>((const unsigned int*)d_out,
                                                    Wl, bl, out);
}